// Round 4
// baseline (227.836 us; speedup 1.0000x reference)
//
#include <hip/hip_runtime.h>
#include <hip/hip_bf16.h>
#include <stdint.h>

#define EMBED 1024
#define NH 16
#define HD 64
#define BATCH 2
#define QLEN 2048
#define CLEN 2048

typedef short short8 __attribute__((ext_vector_type(8)));
typedef unsigned short ushort8v __attribute__((ext_vector_type(8)));
typedef float f32x4 __attribute__((ext_vector_type(4)));
typedef float f32x16 __attribute__((ext_vector_type(16)));
typedef uint32_t u32x4 __attribute__((ext_vector_type(4)));

__device__ __forceinline__ void async_load16(const void* g, void* l) {
    __builtin_amdgcn_global_load_lds((const __attribute__((address_space(1))) void*)g,
                                     (__attribute__((address_space(3))) void*)l, 16, 0, 0);
}

__device__ __forceinline__ uint32_t pack2(float a, float b) {
    float2 f{a, b};
    __hip_bfloat162 t = __float22bfloat162_rn(f);
    uint32_t u;
    __builtin_memcpy(&u, &t, 4);
    return u;
}

// ---------------- fp32 -> bf16 convert, both activations in one dispatch ----------------
__global__ void cvt_two(const float* __restrict__ a, __hip_bfloat16* __restrict__ oa,
                        const float* __restrict__ b2, __hip_bfloat16* __restrict__ ob) {
    const float* src = blockIdx.y ? b2 : a;
    __hip_bfloat16* dst = blockIdx.y ? ob : oa;
    int i = (blockIdx.x * 256 + threadIdx.x) * 4;
    float4 v = *(const float4*)(src + i);
    __hip_bfloat16 h[4];
    h[0] = __float2bfloat16(v.x);
    h[1] = __float2bfloat16(v.y);
    h[2] = __float2bfloat16(v.z);
    h[3] = __float2bfloat16(v.w);
    *(ushort4*)(dst + i) = *(const ushort4*)h;
}

// ---------------- all 4 weight transposes in one dispatch: Wt[n][k] = W[k][n] ----------------
__global__ void wtrans4(const float* __restrict__ W0, const float* __restrict__ W1,
                        const float* __restrict__ W2, const float* __restrict__ W3,
                        __hip_bfloat16* __restrict__ T0, __hip_bfloat16* __restrict__ T1,
                        __hip_bfloat16* __restrict__ T2, __hip_bfloat16* __restrict__ T3) {
    const int z = blockIdx.z;
    const float* W = z == 0 ? W0 : z == 1 ? W1 : z == 2 ? W2 : W3;
    __hip_bfloat16* Wt = z == 0 ? T0 : z == 1 ? T1 : z == 2 ? T2 : T3;
    __shared__ float t[32][33];
    const int tx = threadIdx.x, ty = threadIdx.y;
    const int n0 = blockIdx.x * 32, k0 = blockIdx.y * 32;
#pragma unroll
    for (int r = 0; r < 4; r++)
        t[ty * 4 + r][tx] = W[(size_t)(k0 + ty * 4 + r) * EMBED + n0 + tx];
    __syncthreads();
#pragma unroll
    for (int r = 0; r < 4; r++)
        Wt[(size_t)(n0 + ty * 4 + r) * EMBED + k0 + tx] = __float2bfloat16(t[tx][ty * 4 + r]);
}

// ---------------- V transpose: (b*2048+c, 1024) -> ((b*16+h)*64+d, 2048) ----------------
__global__ __launch_bounds__(256) void vtrans(const __hip_bfloat16* __restrict__ V,
                                              __hip_bfloat16* __restrict__ Vt) {
    __shared__ unsigned short t[64][65];
    const int tid = threadIdx.x;
    const int c0 = blockIdx.x * 64;
    const int b = blockIdx.y >> 4, h = blockIdx.y & 15;
    const int r = tid >> 2;
    const int cs = (tid & 3) * 16;
    const unsigned short* src = (const unsigned short*)V + (size_t)(b * CLEN + c0 + r) * EMBED + h * HD + cs;
    ushort8v v0 = *(const ushort8v*)src;
    ushort8v v1 = *(const ushort8v*)(src + 8);
#pragma unroll
    for (int j = 0; j < 8; j++) { t[r][cs + j] = v0[j]; t[r][cs + 8 + j] = v1[j]; }
    __syncthreads();
    const int d = tid >> 2;
    const int ts = (tid & 3) * 16;
    ushort8v o0, o1;
#pragma unroll
    for (int j = 0; j < 8; j++) { o0[j] = t[ts + j][d]; o1[j] = t[ts + 8 + j][d]; }
    unsigned short* dst = (unsigned short*)Vt + (size_t)((b * NH + h) * HD + d) * CLEN + c0 + ts;
    *(ushort8v*)dst = o0;
    *(ushort8v*)(dst + 8) = o1;
}

__device__ __forceinline__ void store_val(float v, __hip_bfloat16* p) { *p = __float2bfloat16(v); }
__device__ __forceinline__ void store_val(float v, float* p) { *p = v; }

// ---------------- m97-style 128x128 GEMM body (BK=32, B^T layout) ----------------
template <typename OutT>
__device__ __forceinline__ void gemm128_body(
    const __hip_bfloat16* __restrict__ A, const __hip_bfloat16* __restrict__ Bt,
    const float* __restrict__ bias, OutT* __restrict__ C,
    int N, int m0, int n0, int cb,
    __hip_bfloat16* As, __hip_bfloat16* Bs) {
    const int K = EMBED;
    const int tid = threadIdx.x;
    const int wave = __builtin_amdgcn_readfirstlane(tid >> 6);
    const int lane = tid & 63, l15 = lane & 15, quad = lane >> 4;
    const int wm = (wave >> 1) * 64, wn = (wave & 1) * 64;
    const int srow = tid >> 2, sseg = (tid & 3) * 8;
    f32x4 acc[4][4] = {};
    for (int k0 = 0; k0 < K; k0 += 32) {
        __syncthreads();
#pragma unroll
        for (int s = 0; s < 2; s++) {
            async_load16(A + (size_t)(m0 + s * 64 + srow) * K + k0 + sseg,
                         As + (size_t)(s * 256 + wave * 64) * 8);
            async_load16(Bt + (size_t)(n0 + s * 64 + srow) * K + k0 + sseg,
                         Bs + (size_t)(s * 256 + wave * 64) * 8);
        }
        __syncthreads();
        short8 af[4], bf[4];
#pragma unroll
        for (int t = 0; t < 4; t++) {
            af[t] = *(const short8*)(As + (wm + t * 16 + l15) * 32 + quad * 8);
            bf[t] = *(const short8*)(Bs + (wn + t * 16 + l15) * 32 + quad * 8);
        }
#pragma unroll
        for (int mt = 0; mt < 4; mt++)
#pragma unroll
            for (int nt = 0; nt < 4; nt++)
                acc[mt][nt] = __builtin_amdgcn_mfma_f32_16x16x32_bf16(af[mt], bf[nt], acc[mt][nt], 0, 0, 0);
    }
#pragma unroll
    for (int mt = 0; mt < 4; mt++) {
#pragma unroll
        for (int nt = 0; nt < 4; nt++) {
            const int c = cb + wn + nt * 16 + l15;
            const float bvv = bias[c];
            const int r0 = m0 + wm + mt * 16 + quad * 4;
#pragma unroll
            for (int r = 0; r < 4; r++)
                store_val(acc[mt][nt][r] + bvv, C + (size_t)(r0 + r) * N + c);
        }
    }
}

// ---------------- fused Q + KV projections: 768 blocks of 128x128 ----------------
__global__ __launch_bounds__(256, 3) void proj128(
    const __hip_bfloat16* __restrict__ qbf, const __hip_bfloat16* __restrict__ cbf,
    const __hip_bfloat16* __restrict__ Wqt, const __hip_bfloat16* __restrict__ Wkvt,
    const float* __restrict__ bq, const float* __restrict__ bk, const float* __restrict__ bv,
    __hip_bfloat16* __restrict__ Qp, __hip_bfloat16* __restrict__ Kp, __hip_bfloat16* __restrict__ Vp) {
    __shared__ __hip_bfloat16 As[128 * 32];
    __shared__ __hip_bfloat16 Bs[128 * 32];
    const int blk = blockIdx.x;
    const __hip_bfloat16 *A, *Bt;
    int m0, n0;
    if (blk < 256) {
        A = qbf; Bt = Wqt; m0 = (blk >> 3) * 128; n0 = (blk & 7) * 128;
    } else {
        const int f = blk - 256;
        A = cbf; Bt = Wkvt; m0 = (f >> 4) * 128; n0 = (f & 15) * 128;
    }
    const float* bias;
    __hip_bfloat16* C;
    int cb;
    if (blk < 256) { bias = bq; C = Qp; cb = n0; }
    else if (n0 < 1024) { bias = bk; C = Kp; cb = n0; }
    else { bias = bv; C = Vp; cb = n0 - 1024; }
    gemm128_body<__hip_bfloat16>(A, Bt, bias, C, 1024, m0, n0, cb, As, Bs);
}

// ---------------- 64x128-tile GEMM body for output projection ----------------
__global__ __launch_bounds__(256, 4) void oproj(
    const __hip_bfloat16* __restrict__ A, const __hip_bfloat16* __restrict__ Bt,
    const float* __restrict__ bias, float* __restrict__ C) {
    __shared__ __hip_bfloat16 As[64 * 32];
    __shared__ __hip_bfloat16 Bs[128 * 32];
    const int K = EMBED, N = EMBED;
    const int m0 = blockIdx.y * 64, n0 = blockIdx.x * 128;
    const int tid = threadIdx.x;
    const int wave = __builtin_amdgcn_readfirstlane(tid >> 6);
    const int lane = tid & 63, l15 = lane & 15, quad = lane >> 4;
    const int wm = (wave & 1) * 32, wn = (wave >> 1) * 64;
    const int srow = tid >> 2, sseg = (tid & 3) * 8;
    f32x4 acc[2][4] = {};
    for (int k0 = 0; k0 < K; k0 += 32) {
        __syncthreads();
        async_load16(A + (size_t)(m0 + srow) * K + k0 + sseg, As + (size_t)(wave * 64) * 8);
#pragma unroll
        for (int s = 0; s < 2; s++)
            async_load16(Bt + (size_t)(n0 + s * 64 + srow) * K + k0 + sseg,
                         Bs + (size_t)(s * 256 + wave * 64) * 8);
        __syncthreads();
        short8 af[2], bf[4];
#pragma unroll
        for (int t = 0; t < 2; t++)
            af[t] = *(const short8*)(As + (wm + t * 16 + l15) * 32 + quad * 8);
#pragma unroll
        for (int t = 0; t < 4; t++)
            bf[t] = *(const short8*)(Bs + (wn + t * 16 + l15) * 32 + quad * 8);
#pragma unroll
        for (int mt = 0; mt < 2; mt++)
#pragma unroll
            for (int nt = 0; nt < 4; nt++)
                acc[mt][nt] = __builtin_amdgcn_mfma_f32_16x16x32_bf16(af[mt], bf[nt], acc[mt][nt], 0, 0, 0);
    }
#pragma unroll
    for (int mt = 0; mt < 2; mt++) {
#pragma unroll
        for (int nt = 0; nt < 4; nt++) {
            const int c = n0 + wn + nt * 16 + l15;
            const float bvv = bias[c];
            const int r0 = m0 + wm + mt * 16 + quad * 4;
#pragma unroll
            for (int r = 0; r < 4; r++)
                C[(size_t)(r0 + r) * N + c] = acc[mt][nt][r] + bvv;
        }
    }
}

// ---------------- flash attention, 32x32x16 MFMA, S^T formulation ----------------
// S^T = K·Q^T (q in lanes), per-lane deferred softmax, P C-layout -> B-layout via
// cndmask + shfl_xor(32) (no LDS round trip), O^T = V^T·P^T.
// Block = 128 threads (2 waves), each wave owns 32 q; grid (2048/64, 32) = 1024 blocks.
__global__ __launch_bounds__(128, 2) void flash_attn(
    const __hip_bfloat16* __restrict__ Q, const __hip_bfloat16* __restrict__ K,
    const __hip_bfloat16* __restrict__ Vt, __hip_bfloat16* __restrict__ O) {
    __shared__ __hip_bfloat16 Ks[64 * 64];
    __shared__ __hip_bfloat16 Vs[64 * 64];
    const int tid = threadIdx.x;
    const int wq = __builtin_amdgcn_readfirstlane(tid >> 6);
    const int lane = tid & 63;
    const int l31 = lane & 31;
    const int hbit = lane >> 5;
    const int b = blockIdx.y >> 4, h = blockIdx.y & 15;
    const int q0 = blockIdx.x * 64;
    const size_t kbase = (size_t)b * CLEN * EMBED + (size_t)h * HD;
    const size_t vtbase = (size_t)((b * NH + h) * HD) * CLEN;
    const int srow = tid >> 3;                // 0..15
    const int sg = (tid & 7) ^ (srow & 7);    // XOR-swizzled source granule
    const int ldsoff = (tid & 64) * 8;        // wave-uniform base (elems)

    // Q B-fragments direct from global: B[k=d][n=q], k = 16*kc + 8*hbit + j
    const __hip_bfloat16* qptr =
        Q + (size_t)(b * QLEN + q0 + wq * 32 + l31) * EMBED + h * HD + hbit * 8;
    short8 qf[4];
#pragma unroll
    for (int t = 0; t < 4; t++) qf[t] = *(const short8*)(qptr + t * 16);

    f32x16 o[2] = {};
    float lsum = 0.f;
    const float CEXP = 0.125f * 1.44269504f;  // 1/sqrt(64) folded into exp2

    for (int c0 = 0; c0 < CLEN; c0 += 64) {
        __syncthreads();
#pragma unroll
        for (int i = 0; i < 4; i++) {
            async_load16(K + kbase + (size_t)(c0 + i * 16 + srow) * EMBED + sg * 8,
                         Ks + i * 1024 + ldsoff);
            async_load16(Vt + vtbase + (size_t)(i * 16 + srow) * CLEN + c0 + sg * 8,
                         Vs + i * 1024 + ldsoff);
        }
        __syncthreads();

#pragma unroll
        for (int mc = 0; mc < 2; mc++) {
            // S^T tile: A = K rows (c), B = Q; C cols = q (lane&31)
            const int row = mc * 32 + l31;
            const __hip_bfloat16* kr = Ks + row * 64;
            f32x16 s = {};
#pragma unroll
            for (int kc = 0; kc < 4; kc++) {
                short8 kf = *(const short8*)(kr + ((2 * kc + hbit) ^ (row & 7)) * 8);
                s = __builtin_amdgcn_mfma_f32_32x32x16_bf16(kf, qf[kc], s, 0, 0, 0);
            }
            // exp (deferred softmax) + pack to bf16x2 dwords
            uint32_t dw[8];
#pragma unroll
            for (int i = 0; i < 8; i++) {
                const float p0 = __builtin_amdgcn_exp2f(s[2 * i] * CEXP);
                const float p1 = __builtin_amdgcn_exp2f(s[2 * i + 1] * CEXP);
                lsum += p0 + p1;
                dw[i] = pack2(p0, p1);
            }
            // C-layout -> B-layout transform (in-register) + PV MFMA
#pragma unroll
            for (int tp = 0; tp < 2; tp++) {
                const uint32_t a0 = hbit ? dw[4 * tp + 2] : dw[4 * tp + 0];
                const uint32_t a1 = hbit ? dw[4 * tp + 3] : dw[4 * tp + 1];
                const uint32_t b0 = hbit ? dw[4 * tp + 0] : dw[4 * tp + 2];
                const uint32_t b1 = hbit ? dw[4 * tp + 1] : dw[4 * tp + 3];
                const uint32_t x0 = (uint32_t)__shfl_xor((int)b0, 32);
                const uint32_t x1 = (uint32_t)__shfl_xor((int)b1, 32);
                u32x4 fb;
                fb[0] = hbit ? x0 : a0;
                fb[1] = hbit ? x1 : a1;
                fb[2] = hbit ? a0 : x0;
                fb[3] = hbit ? a1 : x1;
                const short8 pfr = __builtin_bit_cast(short8, fb);
                const int kc = mc * 2 + tp;
#pragma unroll
                for (int dm = 0; dm < 2; dm++) {
                    const int vrow = dm * 32 + l31;
                    short8 vf = *(const short8*)(Vs + vrow * 64 + ((2 * kc + hbit) ^ (vrow & 7)) * 8);
                    o[dm] = __builtin_amdgcn_mfma_f32_32x32x16_bf16(vf, pfr, o[dm], 0, 0, 0);
                }
            }
        }
    }

    // epilogue: combine half-lane partial denominators, normalize, store
    lsum += __shfl_xor(lsum, 32);
    const float inv = 1.0f / lsum;
    const int q = q0 + wq * 32 + l31;
    __hip_bfloat16* orow = O + (size_t)(b * QLEN + q) * EMBED + h * HD;
#pragma unroll
    for (int dm = 0; dm < 2; dm++) {
#pragma unroll
        for (int g = 0; g < 4; g++) {
            __hip_bfloat16 ob[4];
#pragma unroll
            for (int r = 0; r < 4; r++) ob[r] = __float2bfloat16(o[dm][g * 4 + r] * inv);
            *(ushort4*)(orow + dm * 32 + hbit * 4 + g * 8) = *(const ushort4*)ob;
        }
    }
}

extern "C" void kernel_launch(void* const* d_in, const int* in_sizes, int n_in,
                              void* d_out, int out_size, void* d_ws, size_t ws_size,
                              hipStream_t stream) {
    const float* query = (const float*)d_in[0];
    const float* context = (const float*)d_in[1];
    const float* Wq = (const float*)d_in[2];
    const float* bq = (const float*)d_in[3];
    const float* Wk = (const float*)d_in[4];
    const float* bk = (const float*)d_in[5];
    const float* Wv = (const float*)d_in[6];
    const float* bv = (const float*)d_in[7];
    const float* Wo = (const float*)d_in[8];
    const float* bo = (const float*)d_in[9];
    float* out = (float*)d_out;

    const int NTOK = BATCH * QLEN;   // 4096
    const int NACT = NTOK * EMBED;   // 4,194,304
    const int NW = EMBED * EMBED;    // 1,048,576

    __hip_bfloat16* qbf = (__hip_bfloat16*)d_ws;
    __hip_bfloat16* cbf = qbf + NACT;
    __hip_bfloat16* Wqt = cbf + NACT;
    __hip_bfloat16* Wkt = Wqt + NW;   // Wkt,Wvt contiguous = fused 2048x1024 B^T
    __hip_bfloat16* Wvt = Wkt + NW;
    __hip_bfloat16* Wot = Wvt + NW;
    __hip_bfloat16* Qp = Wot + NW;
    __hip_bfloat16* Kp = Qp + NACT;
    __hip_bfloat16* Vtr = Kp + NACT;
    __hip_bfloat16* att = Vtr + NACT;  // V-proj temp, then attended output

    cvt_two<<<dim3(NACT / 1024, 2), 256, 0, stream>>>(query, qbf, context, cbf);
    wtrans4<<<dim3(32, 32, 4), dim3(32, 8), 0, stream>>>(Wq, Wk, Wv, Wo, Wqt, Wkt, Wvt, Wot);

    // Q + K + V projections, one dispatch: 256 Q-blocks + 512 KV-blocks of 128x128
    proj128<<<768, 256, 0, stream>>>(qbf, cbf, Wqt, Wkt, bq, bk, bv, Qp, Kp, att);

    // V (att temp) -> Vtr transposed per head
    vtrans<<<dim3(CLEN / 64, BATCH * NH), 256, 0, stream>>>(att, Vtr);

    flash_attn<<<dim3(QLEN / 64, BATCH * NH), 128, 0, stream>>>(Qp, Kp, Vtr, att);

    oproj<<<dim3(EMBED / 128, NTOK / 64), 256, 0, stream>>>(att, Wot, bo, out);
}

// Round 7
// 212.317 us; speedup vs baseline: 1.0731x; 1.0731x over previous
//
#include <hip/hip_runtime.h>
#include <hip/hip_bf16.h>
#include <stdint.h>

#define EMBED 1024
#define NH 16
#define HD 64
#define BATCH 2
#define QLEN 2048
#define CLEN 2048

typedef short short8 __attribute__((ext_vector_type(8)));
typedef float f32x4 __attribute__((ext_vector_type(4)));
typedef float f32x16 __attribute__((ext_vector_type(16)));
typedef uint32_t u32x4 __attribute__((ext_vector_type(4)));

__device__ __forceinline__ void async_load16(const void* g, void* l) {
    __builtin_amdgcn_global_load_lds((const __attribute__((address_space(1))) void*)g,
                                     (__attribute__((address_space(3))) void*)l, 16, 0, 0);
}

__device__ __forceinline__ uint32_t pack2(float a, float b) {
    float2 f{a, b};
    __hip_bfloat162 t = __float22bfloat162_rn(f);
    uint32_t u;
    __builtin_memcpy(&u, &t, 4);
    return u;
}

// ---------------- prep: activations cvt (y=0,1) + weight transposes (y=2..5) ----------------
__global__ void prep(const float* __restrict__ query, const float* __restrict__ context,
                     __hip_bfloat16* __restrict__ qbf, __hip_bfloat16* __restrict__ cbf,
                     const float* __restrict__ W0, const float* __restrict__ W1,
                     const float* __restrict__ W2, const float* __restrict__ W3,
                     __hip_bfloat16* __restrict__ T0, __hip_bfloat16* __restrict__ T1,
                     __hip_bfloat16* __restrict__ T2, __hip_bfloat16* __restrict__ T3) {
    const int y = blockIdx.y;
    const int tid = threadIdx.x;
    if (y < 2) {
        const float* src = y ? context : query;
        __hip_bfloat16* dst = y ? cbf : qbf;
        // float4-index space: 1024 blocks x 4 iters x 256 threads = 1,048,576 float4s = NACT
#pragma unroll
        for (int k = 0; k < 4; k++) {
            const int i = (blockIdx.x * 1024 + k * 256 + tid) * 4;
            float4 v = *(const float4*)(src + i);
            __hip_bfloat16 h[4];
            h[0] = __float2bfloat16(v.x);
            h[1] = __float2bfloat16(v.y);
            h[2] = __float2bfloat16(v.z);
            h[3] = __float2bfloat16(v.w);
            *(ushort4*)(dst + i) = *(const ushort4*)h;
        }
    } else {
        const int z = y - 2;
        const float* W = z == 0 ? W0 : z == 1 ? W1 : z == 2 ? W2 : W3;
        __hip_bfloat16* Wt = z == 0 ? T0 : z == 1 ? T1 : z == 2 ? T2 : T3;
        __shared__ float t[32][33];
        const int tx = tid & 31, ty = tid >> 5;
        const int n0 = (blockIdx.x & 31) * 32, k0 = (blockIdx.x >> 5) * 32;
#pragma unroll
        for (int r = 0; r < 4; r++)
            t[ty * 4 + r][tx] = W[(size_t)(k0 + ty * 4 + r) * EMBED + n0 + tx];
        __syncthreads();
#pragma unroll
        for (int r = 0; r < 4; r++)
            Wt[(size_t)(n0 + ty * 4 + r) * EMBED + k0 + tx] = __float2bfloat16(t[tx][ty * 4 + r]);
    }
}

// ---------------- 128x128 GEMM accumulate body (BK=32, B^T layout, K=1024) ----------------
__device__ __forceinline__ void gemm128_acc(
    const __hip_bfloat16* __restrict__ A, const __hip_bfloat16* __restrict__ Bt,
    int m0, int n0, __hip_bfloat16* As, __hip_bfloat16* Bs, f32x4 acc[4][4]) {
    const int K = EMBED;
    const int tid = threadIdx.x;
    const int wave = __builtin_amdgcn_readfirstlane(tid >> 6);
    const int lane = tid & 63, l15 = lane & 15, quad = lane >> 4;
    const int wm = (wave >> 1) * 64, wn = (wave & 1) * 64;
    const int srow = tid >> 2, sseg = (tid & 3) * 8;
    for (int k0 = 0; k0 < K; k0 += 32) {
        __syncthreads();
#pragma unroll
        for (int s = 0; s < 2; s++) {
            async_load16(A + (size_t)(m0 + s * 64 + srow) * K + k0 + sseg,
                         As + (size_t)(s * 256 + wave * 64) * 8);
            async_load16(Bt + (size_t)(n0 + s * 64 + srow) * K + k0 + sseg,
                         Bs + (size_t)(s * 256 + wave * 64) * 8);
        }
        __syncthreads();
        short8 af[4], bf[4];
#pragma unroll
        for (int t = 0; t < 4; t++) {
            af[t] = *(const short8*)(As + (wm + t * 16 + l15) * 32 + quad * 8);
            bf[t] = *(const short8*)(Bs + (wn + t * 16 + l15) * 32 + quad * 8);
        }
#pragma unroll
        for (int mt = 0; mt < 4; mt++)
#pragma unroll
            for (int nt = 0; nt < 4; nt++)
                acc[mt][nt] = __builtin_amdgcn_mfma_f32_16x16x32_bf16(af[mt], bf[nt], acc[mt][nt], 0, 0, 0);
    }
}

// ---------------- fused Q + K + V projections (V stored transposed) ----------------
__global__ __launch_bounds__(256, 3) void proj128(
    const __hip_bfloat16* __restrict__ qbf, const __hip_bfloat16* __restrict__ cbf,
    const __hip_bfloat16* __restrict__ Wqt, const __hip_bfloat16* __restrict__ Wkvt,
    const float* __restrict__ bq, const float* __restrict__ bk, const float* __restrict__ bv,
    __hip_bfloat16* __restrict__ Qp, __hip_bfloat16* __restrict__ Kp, __hip_bfloat16* __restrict__ Vtr) {
    __shared__ __hip_bfloat16 As[128 * 32];
    __shared__ __hip_bfloat16 Bs[128 * 32];
    const int blk = blockIdx.x;
    const __hip_bfloat16 *A, *Bt;
    int m0, n0;
    if (blk < 256) {
        A = qbf; Bt = Wqt; m0 = (blk >> 3) * 128; n0 = (blk & 7) * 128;
    } else {
        const int f = blk - 256;
        A = cbf; Bt = Wkvt; m0 = (f >> 4) * 128; n0 = (f & 15) * 128;
    }
    f32x4 acc[4][4] = {};
    gemm128_acc(A, Bt, m0, n0, As, Bs, acc);

    const int tid = threadIdx.x;
    const int wave = __builtin_amdgcn_readfirstlane(tid >> 6);
    const int lane = tid & 63, l15 = lane & 15, quad = lane >> 4;
    const int wm = (wave >> 1) * 64, wn = (wave & 1) * 64;

    if (blk >= 256 && n0 >= 1024) {
        // V block: write transposed into Vtr[(b*16+h)*64+d][c]
        const int cb = n0 - 1024;
        const int b2 = m0 >> 11;
        const int tokbase = (m0 & 2047) + wm;
#pragma unroll
        for (int mt = 0; mt < 4; mt++) {
#pragma unroll
            for (int nt = 0; nt < 4; nt++) {
                const int col = cb + wn + nt * 16 + l15;  // h*64+d, 0..1023
                const float bvv = bv[col];
                const int tok = tokbase + mt * 16 + quad * 4;
                __hip_bfloat16 vb[4];
#pragma unroll
                for (int r = 0; r < 4; r++) vb[r] = __float2bfloat16(acc[mt][nt][r] + bvv);
                *(ushort4*)(Vtr + (size_t)(b2 * 1024 + col) * CLEN + tok) = *(const ushort4*)vb;
            }
        }
    } else {
        const float* bias = (blk < 256) ? bq : bk;
        __hip_bfloat16* C = (blk < 256) ? Qp : Kp;
#pragma unroll
        for (int mt = 0; mt < 4; mt++) {
#pragma unroll
            for (int nt = 0; nt < 4; nt++) {
                const int c = n0 + wn + nt * 16 + l15;
                const float bvv = bias[c];
                const int r0 = m0 + wm + mt * 16 + quad * 4;
#pragma unroll
                for (int r = 0; r < 4; r++)
                    C[(size_t)(r0 + r) * 1024 + c] = __float2bfloat16(acc[mt][nt][r] + bvv);
            }
        }
    }
}

// ---------------- output projection: 64x128 tiles, fp32 out ----------------
__global__ __launch_bounds__(256, 4) void oproj(
    const __hip_bfloat16* __restrict__ A, const __hip_bfloat16* __restrict__ Bt,
    const float* __restrict__ bias, float* __restrict__ C) {
    __shared__ __hip_bfloat16 As[64 * 32];
    __shared__ __hip_bfloat16 Bs[128 * 32];
    const int K = EMBED, N = EMBED;
    const int m0 = blockIdx.y * 64, n0 = blockIdx.x * 128;
    const int tid = threadIdx.x;
    const int wave = __builtin_amdgcn_readfirstlane(tid >> 6);
    const int lane = tid & 63, l15 = lane & 15, quad = lane >> 4;
    const int wm = (wave & 1) * 32, wn = (wave >> 1) * 64;
    const int srow = tid >> 2, sseg = (tid & 3) * 8;
    f32x4 acc[2][4] = {};
    for (int k0 = 0; k0 < K; k0 += 32) {
        __syncthreads();
        async_load16(A + (size_t)(m0 + srow) * K + k0 + sseg, As + (size_t)(wave * 64) * 8);
#pragma unroll
        for (int s = 0; s < 2; s++)
            async_load16(Bt + (size_t)(n0 + s * 64 + srow) * K + k0 + sseg,
                         Bs + (size_t)(s * 256 + wave * 64) * 8);
        __syncthreads();
        short8 af[2], bf[4];
#pragma unroll
        for (int t = 0; t < 2; t++)
            af[t] = *(const short8*)(As + (wm + t * 16 + l15) * 32 + quad * 8);
#pragma unroll
        for (int t = 0; t < 4; t++)
            bf[t] = *(const short8*)(Bs + (wn + t * 16 + l15) * 32 + quad * 8);
#pragma unroll
        for (int mt = 0; mt < 2; mt++)
#pragma unroll
            for (int nt = 0; nt < 4; nt++)
                acc[mt][nt] = __builtin_amdgcn_mfma_f32_16x16x32_bf16(af[mt], bf[nt], acc[mt][nt], 0, 0, 0);
    }
#pragma unroll
    for (int mt = 0; mt < 2; mt++) {
#pragma unroll
        for (int nt = 0; nt < 4; nt++) {
            const int c = n0 + wn + nt * 16 + l15;
            const float bvv = bias[c];
            const int r0 = m0 + wm + mt * 16 + quad * 4;
#pragma unroll
            for (int r = 0; r < 4; r++)
                C[(size_t)(r0 + r) * N + c] = acc[mt][nt][r] + bvv;
        }
    }
}

// ---------------- flash attention: 32x32x16 MFMA, S^T form, c-split x2 ----------------
// Block 256 = 4 waves: wave = (wc<<1)|wq. wq selects 32-q half of the 64-q tile,
// wc selects which half of CLEN this wave accumulates (deferred softmax => partial
// O^T and lsum are additive). Two LDS K/V regions let both c-halves run concurrently.
// Grid (2048/64, 32) = 1024 blocks -> 4 blocks/CU, 16 waves/CU.
__global__ __launch_bounds__(256, 4) void flash_attn(
    const __hip_bfloat16* __restrict__ Q, const __hip_bfloat16* __restrict__ K,
    const __hip_bfloat16* __restrict__ Vt, __hip_bfloat16* __restrict__ O) {
    __shared__ __hip_bfloat16 Ks[2][64 * 64];
    __shared__ __hip_bfloat16 Vs[2][64 * 64];
    const int tid = threadIdx.x;
    const int wave = __builtin_amdgcn_readfirstlane(tid >> 6);
    const int wq = wave & 1, wc = wave >> 1;
    const int lane = tid & 63, l31 = lane & 31, hbit = lane >> 5;
    const int b = blockIdx.y >> 4, h = blockIdx.y & 15;
    const int q0 = blockIdx.x * 64;
    const size_t kbase = (size_t)b * CLEN * EMBED + (size_t)h * HD;
    const size_t vtbase = (size_t)((b * NH + h) * HD) * CLEN;
    const int srow8 = lane >> 3;           // 0..7
    const int sg = (lane & 7) ^ srow8;     // XOR-swizzled source granule
    __hip_bfloat16* stK = Ks[wc];
    __hip_bfloat16* stV = Vs[wc];

    // Q B-fragments direct from global (B[k=d][n=q], k = 16*kc + 8*hbit + j)
    const __hip_bfloat16* qptr =
        Q + (size_t)(b * QLEN + q0 + wq * 32 + l31) * EMBED + h * HD + hbit * 8;
    short8 qf[4];
#pragma unroll
    for (int t = 0; t < 4; t++) qf[t] = *(const short8*)(qptr + t * 16);

    f32x16 o[2] = {};
    float lsum = 0.f;
    const float CEXP = 0.125f * 1.44269504f;  // 1/sqrt(64) folded into exp2
    const int cbase = wc * (CLEN / 2);

    for (int t = 0; t < 16; ++t) {
        const int c0 = cbase + t * 64;
        __syncthreads();
        // LDS dest must be WAVE-UNIFORM (HW adds lane*16B): each issue covers
        // 8 rows x 64 cols (1024 B). Lane L -> row i*8+(L>>3), phys granule L&7;
        // matching global col = ((L&7) ^ (row&7)) * 8 = sg*8.
        if (wq == 0) {
#pragma unroll
            for (int i = 0; i < 8; i++)
                async_load16(K + kbase + (size_t)(c0 + i * 8 + srow8) * EMBED + sg * 8,
                             stK + i * 512);
        } else {
#pragma unroll
            for (int i = 0; i < 8; i++)
                async_load16(Vt + vtbase + (size_t)(i * 8 + srow8) * CLEN + c0 + sg * 8,
                             stV + i * 512);
        }
        __syncthreads();

#pragma unroll
        for (int mc = 0; mc < 2; mc++) {
            const int row = mc * 32 + l31;
            const __hip_bfloat16* kr = stK + row * 64;
            f32x16 s = {};
#pragma unroll
            for (int kc = 0; kc < 4; kc++) {
                short8 kf = *(const short8*)(kr + ((2 * kc + hbit) ^ (row & 7)) * 8);
                s = __builtin_amdgcn_mfma_f32_32x32x16_bf16(kf, qf[kc], s, 0, 0, 0);
            }
            uint32_t dw[8];
#pragma unroll
            for (int i = 0; i < 8; i++) {
                const float p0 = __builtin_amdgcn_exp2f(s[2 * i] * CEXP);
                const float p1 = __builtin_amdgcn_exp2f(s[2 * i + 1] * CEXP);
                lsum += p0 + p1;
                dw[i] = pack2(p0, p1);
            }
            // C-layout -> B-layout (in-register) + PV MFMA
#pragma unroll
            for (int tp = 0; tp < 2; tp++) {
                const uint32_t a0 = hbit ? dw[4 * tp + 2] : dw[4 * tp + 0];
                const uint32_t a1 = hbit ? dw[4 * tp + 3] : dw[4 * tp + 1];
                const uint32_t b0 = hbit ? dw[4 * tp + 0] : dw[4 * tp + 2];
                const uint32_t b1 = hbit ? dw[4 * tp + 1] : dw[4 * tp + 3];
                const uint32_t x0 = (uint32_t)__shfl_xor((int)b0, 32);
                const uint32_t x1 = (uint32_t)__shfl_xor((int)b1, 32);
                u32x4 fb;
                fb[0] = hbit ? x0 : a0;
                fb[1] = hbit ? x1 : a1;
                fb[2] = hbit ? a0 : x0;
                fb[3] = hbit ? a1 : x1;
                const short8 pfr = __builtin_bit_cast(short8, fb);
                const int kc2 = mc * 2 + tp;
#pragma unroll
                for (int dm = 0; dm < 2; dm++) {
                    const int vrow = dm * 32 + l31;
                    short8 vf = *(const short8*)(stV + vrow * 64 + ((2 * kc2 + hbit) ^ (vrow & 7)) * 8);
                    o[dm] = __builtin_amdgcn_mfma_f32_32x32x16_bf16(vf, pfr, o[dm], 0, 0, 0);
                }
            }
        }
    }

    // ---- combine c-halves (additive), then normalize & store ----
    __syncthreads();
    float4* scr4 = (float4*)&Ks[0][0];   // 8 chunks x 128 lanes x float4 = 16 KB
    float* scrl = (float*)&Vs[0][0];     // 128 floats
    if (wc == 1) {
#pragma unroll
        for (int i = 0; i < 8; i++) {
            float4 c4;
            c4.x = o[i >> 2][(i & 3) * 4 + 0];
            c4.y = o[i >> 2][(i & 3) * 4 + 1];
            c4.z = o[i >> 2][(i & 3) * 4 + 2];
            c4.w = o[i >> 2][(i & 3) * 4 + 3];
            scr4[i * 128 + wq * 64 + lane] = c4;
        }
        scrl[wq * 64 + lane] = lsum;
    }
    __syncthreads();
    if (wc == 0) {
        lsum += scrl[wq * 64 + lane];
#pragma unroll
        for (int i = 0; i < 8; i++) {
            float4 p = scr4[i * 128 + wq * 64 + lane];
            o[i >> 2][(i & 3) * 4 + 0] += p.x;
            o[i >> 2][(i & 3) * 4 + 1] += p.y;
            o[i >> 2][(i & 3) * 4 + 2] += p.z;
            o[i >> 2][(i & 3) * 4 + 3] += p.w;
        }
        lsum += __shfl_xor(lsum, 32);
        const float inv = 1.0f / lsum;
        const int q = q0 + wq * 32 + l31;
        __hip_bfloat16* orow = O + (size_t)(b * QLEN + q) * EMBED + h * HD;
#pragma unroll
        for (int dm = 0; dm < 2; dm++) {
#pragma unroll
            for (int g = 0; g < 4; g++) {
                __hip_bfloat16 ob[4];
#pragma unroll
                for (int r = 0; r < 4; r++) ob[r] = __float2bfloat16(o[dm][g * 4 + r] * inv);
                *(ushort4*)(orow + dm * 32 + hbit * 4 + g * 8) = *(const ushort4*)ob;
            }
        }
    }
}

extern "C" void kernel_launch(void* const* d_in, const int* in_sizes, int n_in,
                              void* d_out, int out_size, void* d_ws, size_t ws_size,
                              hipStream_t stream) {
    const float* query = (const float*)d_in[0];
    const float* context = (const float*)d_in[1];
    const float* Wq = (const float*)d_in[2];
    const float* bq = (const float*)d_in[3];
    const float* Wk = (const float*)d_in[4];
    const float* bk = (const float*)d_in[5];
    const float* Wv = (const float*)d_in[6];
    const float* bv = (const float*)d_in[7];
    const float* Wo = (const float*)d_in[8];
    const float* bo = (const float*)d_in[9];
    float* out = (float*)d_out;

    const int NTOK = BATCH * QLEN;   // 4096
    const int NACT = NTOK * EMBED;   // 4,194,304
    const int NW = EMBED * EMBED;    // 1,048,576

    __hip_bfloat16* qbf = (__hip_bfloat16*)d_ws;
    __hip_bfloat16* cbf = qbf + NACT;
    __hip_bfloat16* Wqt = cbf + NACT;
    __hip_bfloat16* Wkt = Wqt + NW;   // Wkt,Wvt contiguous = fused 2048x1024 B^T
    __hip_bfloat16* Wvt = Wkt + NW;
    __hip_bfloat16* Wot = Wvt + NW;
    __hip_bfloat16* Qp = Wot + NW;
    __hip_bfloat16* Kp = Qp + NACT;
    __hip_bfloat16* Vtr = Kp + NACT;   // V^T ((b*16+h)*64+d) x 2048, written by proj128
    __hip_bfloat16* att = Vtr + NACT;  // attended output

    prep<<<dim3(1024, 6), 256, 0, stream>>>(query, context, qbf, cbf,
                                            Wq, Wk, Wv, Wo, Wqt, Wkt, Wvt, Wot);

    // Q + K + V projections, one dispatch; V written transposed
    proj128<<<768, 256, 0, stream>>>(qbf, cbf, Wqt, Wkt, bq, bk, bv, Qp, Kp, Vtr);

    flash_attn<<<dim3(QLEN / 64, BATCH * NH), 256, 0, stream>>>(Qp, Kp, Vtr, att);

    oproj<<<dim3(EMBED / 128, NTOK / 64), 256, 0, stream>>>(att, Wot, bo, out);
}

// Round 8
// 205.557 us; speedup vs baseline: 1.1084x; 1.0329x over previous
//
#include <hip/hip_runtime.h>
#include <hip/hip_bf16.h>
#include <stdint.h>

#define EMBED 1024
#define NH 16
#define HD 64
#define BATCH 2
#define QLEN 2048
#define CLEN 2048

typedef short short8 __attribute__((ext_vector_type(8)));
typedef float f32x4 __attribute__((ext_vector_type(4)));
typedef float f32x16 __attribute__((ext_vector_type(16)));
typedef uint32_t u32x4 __attribute__((ext_vector_type(4)));

// softmax scale folded into Q projection: 1/sqrt(64) * log2(e)
#define QSCALE 0.18033688f

__device__ __forceinline__ void async_load16(const void* g, void* l) {
    __builtin_amdgcn_global_load_lds((const __attribute__((address_space(1))) void*)g,
                                     (__attribute__((address_space(3))) void*)l, 16, 0, 0);
}

__device__ __forceinline__ uint32_t pack2(float a, float b) {
    float2 f{a, b};
    __hip_bfloat162 t = __float22bfloat162_rn(f);
    uint32_t u;
    __builtin_memcpy(&u, &t, 4);
    return u;
}

// ---------------- prep: activations cvt (y=0,1) + weight transposes (y=2..5) ----------------
__global__ void prep(const float* __restrict__ query, const float* __restrict__ context,
                     __hip_bfloat16* __restrict__ qbf, __hip_bfloat16* __restrict__ cbf,
                     const float* __restrict__ W0, const float* __restrict__ W1,
                     const float* __restrict__ W2, const float* __restrict__ W3,
                     __hip_bfloat16* __restrict__ T0, __hip_bfloat16* __restrict__ T1,
                     __hip_bfloat16* __restrict__ T2, __hip_bfloat16* __restrict__ T3) {
    const int y = blockIdx.y;
    const int tid = threadIdx.x;
    if (y < 2) {
        const float* src = y ? context : query;
        __hip_bfloat16* dst = y ? cbf : qbf;
        // float4-index space: 1024 blocks x 4 iters x 256 threads = 1,048,576 float4s = NACT
#pragma unroll
        for (int k = 0; k < 4; k++) {
            const int i = (blockIdx.x * 1024 + k * 256 + tid) * 4;
            float4 v = *(const float4*)(src + i);
            __hip_bfloat16 h[4];
            h[0] = __float2bfloat16(v.x);
            h[1] = __float2bfloat16(v.y);
            h[2] = __float2bfloat16(v.z);
            h[3] = __float2bfloat16(v.w);
            *(ushort4*)(dst + i) = *(const ushort4*)h;
        }
    } else {
        const int z = y - 2;
        const float* W = z == 0 ? W0 : z == 1 ? W1 : z == 2 ? W2 : W3;
        __hip_bfloat16* Wt = z == 0 ? T0 : z == 1 ? T1 : z == 2 ? T2 : T3;
        __shared__ float t[32][33];
        const int tx = tid & 31, ty = tid >> 5;
        const int n0 = (blockIdx.x & 31) * 32, k0 = (blockIdx.x >> 5) * 32;
#pragma unroll
        for (int r = 0; r < 4; r++)
            t[ty * 4 + r][tx] = W[(size_t)(k0 + ty * 4 + r) * EMBED + n0 + tx];
        __syncthreads();
#pragma unroll
        for (int r = 0; r < 4; r++)
            Wt[(size_t)(n0 + ty * 4 + r) * EMBED + k0 + tx] = __float2bfloat16(t[tx][ty * 4 + r]);
    }
}

// ---------------- 128x128 GEMM accumulate body (BK=32, B^T layout, K=1024) ----------------
__device__ __forceinline__ void gemm128_acc(
    const __hip_bfloat16* __restrict__ A, const __hip_bfloat16* __restrict__ Bt,
    int m0, int n0, __hip_bfloat16* As, __hip_bfloat16* Bs, f32x4 acc[4][4]) {
    const int K = EMBED;
    const int tid = threadIdx.x;
    const int wave = __builtin_amdgcn_readfirstlane(tid >> 6);
    const int lane = tid & 63, l15 = lane & 15, quad = lane >> 4;
    const int wm = (wave >> 1) * 64, wn = (wave & 1) * 64;
    const int srow = tid >> 2, sseg = (tid & 3) * 8;
    for (int k0 = 0; k0 < K; k0 += 32) {
        __syncthreads();
#pragma unroll
        for (int s = 0; s < 2; s++) {
            async_load16(A + (size_t)(m0 + s * 64 + srow) * K + k0 + sseg,
                         As + (size_t)(s * 256 + wave * 64) * 8);
            async_load16(Bt + (size_t)(n0 + s * 64 + srow) * K + k0 + sseg,
                         Bs + (size_t)(s * 256 + wave * 64) * 8);
        }
        __syncthreads();
        short8 af[4], bf[4];
#pragma unroll
        for (int t = 0; t < 4; t++) {
            af[t] = *(const short8*)(As + (wm + t * 16 + l15) * 32 + quad * 8);
            bf[t] = *(const short8*)(Bs + (wn + t * 16 + l15) * 32 + quad * 8);
        }
#pragma unroll
        for (int mt = 0; mt < 4; mt++)
#pragma unroll
            for (int nt = 0; nt < 4; nt++)
                acc[mt][nt] = __builtin_amdgcn_mfma_f32_16x16x32_bf16(af[mt], bf[nt], acc[mt][nt], 0, 0, 0);
    }
}

// ---------------- fused Q + K + V projections (V stored transposed, Q pre-scaled) ----------------
// XCD swizzle: HW assigns block j -> XCD j%8; remap so each XCD runs 96 consecutive
// logical blocks (same A-panel groups + weights stay resident in its 4MB L2).
__global__ __launch_bounds__(256, 3) void proj128(
    const __hip_bfloat16* __restrict__ qbf, const __hip_bfloat16* __restrict__ cbf,
    const __hip_bfloat16* __restrict__ Wqt, const __hip_bfloat16* __restrict__ Wkvt,
    const float* __restrict__ bq, const float* __restrict__ bk, const float* __restrict__ bv,
    __hip_bfloat16* __restrict__ Qp, __hip_bfloat16* __restrict__ Kp, __hip_bfloat16* __restrict__ Vtr) {
    __shared__ __hip_bfloat16 As[128 * 32];
    __shared__ __hip_bfloat16 Bs[128 * 32];
    const int j = blockIdx.x;
    const int blk = (j & 7) * 96 + (j >> 3);
    const __hip_bfloat16 *A, *Bt;
    int m0, n0;
    if (blk < 256) {
        A = qbf; Bt = Wqt; m0 = (blk >> 3) * 128; n0 = (blk & 7) * 128;
    } else {
        const int f = blk - 256;
        A = cbf; Bt = Wkvt; m0 = (f >> 4) * 128; n0 = (f & 15) * 128;
    }
    f32x4 acc[4][4] = {};
    gemm128_acc(A, Bt, m0, n0, As, Bs, acc);

    const int tid = threadIdx.x;
    const int wave = __builtin_amdgcn_readfirstlane(tid >> 6);
    const int lane = tid & 63, l15 = lane & 15, quad = lane >> 4;
    const int wm = (wave >> 1) * 64, wn = (wave & 1) * 64;

    if (blk >= 256 && n0 >= 1024) {
        // V block: write transposed into Vtr[(b*16+h)*64+d][c]
        const int cb = n0 - 1024;
        const int b2 = m0 >> 11;
        const int tokbase = (m0 & 2047) + wm;
#pragma unroll
        for (int mt = 0; mt < 4; mt++) {
#pragma unroll
            for (int nt = 0; nt < 4; nt++) {
                const int col = cb + wn + nt * 16 + l15;  // h*64+d, 0..1023
                const float bvv = bv[col];
                const int tok = tokbase + mt * 16 + quad * 4;
                __hip_bfloat16 vb[4];
#pragma unroll
                for (int r = 0; r < 4; r++) vb[r] = __float2bfloat16(acc[mt][nt][r] + bvv);
                *(ushort4*)(Vtr + (size_t)(b2 * 1024 + col) * CLEN + tok) = *(const ushort4*)vb;
            }
        }
    } else {
        const bool isQ = (blk < 256);
        const float* bias = isQ ? bq : bk;
        __hip_bfloat16* C = isQ ? Qp : Kp;
        const float sc = isQ ? QSCALE : 1.0f;
#pragma unroll
        for (int mt = 0; mt < 4; mt++) {
#pragma unroll
            for (int nt = 0; nt < 4; nt++) {
                const int c = n0 + wn + nt * 16 + l15;
                const float bvv = bias[c];
                const int r0 = m0 + wm + mt * 16 + quad * 4;
#pragma unroll
                for (int r = 0; r < 4; r++)
                    C[(size_t)(r0 + r) * 1024 + c] = __float2bfloat16((acc[mt][nt][r] + bvv) * sc);
            }
        }
    }
}

// ---------------- output projection: 64x128 tiles, fp32 out, XCD swizzle ----------------
__global__ __launch_bounds__(256, 4) void oproj(
    const __hip_bfloat16* __restrict__ A, const __hip_bfloat16* __restrict__ Bt,
    const float* __restrict__ bias, float* __restrict__ C) {
    __shared__ __hip_bfloat16 As[64 * 32];
    __shared__ __hip_bfloat16 Bs[128 * 32];
    const int K = EMBED, N = EMBED;
    const int j = blockIdx.x;
    const int L = (j & 7) * 64 + (j >> 3);
    const int m0 = (L >> 3) * 64, n0 = (L & 7) * 128;
    const int tid = threadIdx.x;
    const int wave = __builtin_amdgcn_readfirstlane(tid >> 6);
    const int lane = tid & 63, l15 = lane & 15, quad = lane >> 4;
    const int wm = (wave & 1) * 32, wn = (wave >> 1) * 64;
    const int srow = tid >> 2, sseg = (tid & 3) * 8;
    f32x4 acc[2][4] = {};
    for (int k0 = 0; k0 < K; k0 += 32) {
        __syncthreads();
        async_load16(A + (size_t)(m0 + srow) * K + k0 + sseg, As + (size_t)(wave * 64) * 8);
#pragma unroll
        for (int s = 0; s < 2; s++)
            async_load16(Bt + (size_t)(n0 + s * 64 + srow) * K + k0 + sseg,
                         Bs + (size_t)(s * 256 + wave * 64) * 8);
        __syncthreads();
        short8 af[2], bf[4];
#pragma unroll
        for (int t = 0; t < 2; t++)
            af[t] = *(const short8*)(As + (wm + t * 16 + l15) * 32 + quad * 8);
#pragma unroll
        for (int t = 0; t < 4; t++)
            bf[t] = *(const short8*)(Bs + (wn + t * 16 + l15) * 32 + quad * 8);
#pragma unroll
        for (int mt = 0; mt < 2; mt++)
#pragma unroll
            for (int nt = 0; nt < 4; nt++)
                acc[mt][nt] = __builtin_amdgcn_mfma_f32_16x16x32_bf16(af[mt], bf[nt], acc[mt][nt], 0, 0, 0);
    }
#pragma unroll
    for (int mt = 0; mt < 2; mt++) {
#pragma unroll
        for (int nt = 0; nt < 4; nt++) {
            const int c = n0 + wn + nt * 16 + l15;
            const float bvv = bias[c];
            const int r0 = m0 + wm + mt * 16 + quad * 4;
#pragma unroll
            for (int r = 0; r < 4; r++)
                C[(size_t)(r0 + r) * N + c] = acc[mt][nt][r] + bvv;
        }
    }
}

// ---------------- flash attention: 32x32x16 MFMA, S^T form, c-split x2 ----------------
// Block 256 = 4 waves: wave = (wc<<1)|wq. Q pre-scaled by 1/sqrt(64)*log2e in proj.
// C->B layout transform via v_permlane32_swap_b32 (gfx950) when available.
// Flat grid 1024 with XCD swizzle: each XCD runs 128 consecutive logical blocks
// = 4 complete heads, so one head's K/V (512KB) stays in its L2.
__global__ __launch_bounds__(256, 4) void flash_attn(
    const __hip_bfloat16* __restrict__ Q, const __hip_bfloat16* __restrict__ K,
    const __hip_bfloat16* __restrict__ Vt, __hip_bfloat16* __restrict__ O) {
    __shared__ __hip_bfloat16 Ks[2][64 * 64];
    __shared__ __hip_bfloat16 Vs[2][64 * 64];
    const int tid = threadIdx.x;
    const int wave = __builtin_amdgcn_readfirstlane(tid >> 6);
    const int wq = wave & 1, wc = wave >> 1;
    const int lane = tid & 63, l31 = lane & 31, hbit = lane >> 5;
    const int j = blockIdx.x;
    const int L = (j & 7) * 128 + (j >> 3);
    const int hy = L >> 5;            // b*16+h
    const int b = hy >> 4, h = hy & 15;
    const int q0 = (L & 31) * 64;
    const size_t kbase = (size_t)b * CLEN * EMBED + (size_t)h * HD;
    const size_t vtbase = (size_t)((b * NH + h) * HD) * CLEN;
    const int srow8 = lane >> 3;           // 0..7
    const int sg = (lane & 7) ^ srow8;     // XOR-swizzled source granule
    __hip_bfloat16* stK = Ks[wc];
    __hip_bfloat16* stV = Vs[wc];

    // Q B-fragments direct from global (B[k=d][n=q], k = 16*kc + 8*hbit + j)
    const __hip_bfloat16* qptr =
        Q + (size_t)(b * QLEN + q0 + wq * 32 + l31) * EMBED + h * HD + hbit * 8;
    short8 qf[4];
#pragma unroll
    for (int t = 0; t < 4; t++) qf[t] = *(const short8*)(qptr + t * 16);

    f32x16 o[2] = {};
    float lsum = 0.f;
    const int cbase = wc * (CLEN / 2);

    for (int t = 0; t < 16; ++t) {
        const int c0 = cbase + t * 64;
        __syncthreads();
        // LDS dest must be WAVE-UNIFORM (HW adds lane*16B): each issue covers
        // 8 rows x 64 cols (1024 B).
        if (wq == 0) {
#pragma unroll
            for (int i = 0; i < 8; i++)
                async_load16(K + kbase + (size_t)(c0 + i * 8 + srow8) * EMBED + sg * 8,
                             stK + i * 512);
        } else {
#pragma unroll
            for (int i = 0; i < 8; i++)
                async_load16(Vt + vtbase + (size_t)(i * 8 + srow8) * CLEN + c0 + sg * 8,
                             stV + i * 512);
        }
        __syncthreads();

#pragma unroll
        for (int mc = 0; mc < 2; mc++) {
            const int row = mc * 32 + l31;
            const __hip_bfloat16* kr = stK + row * 64;
            f32x16 s = {};
#pragma unroll
            for (int kc = 0; kc < 4; kc++) {
                short8 kf = *(const short8*)(kr + ((2 * kc + hbit) ^ (row & 7)) * 8);
                s = __builtin_amdgcn_mfma_f32_32x32x16_bf16(kf, qf[kc], s, 0, 0, 0);
            }
            uint32_t dw[8];
#pragma unroll
            for (int i = 0; i < 8; i++) {
                const float p0 = __builtin_amdgcn_exp2f(s[2 * i]);
                const float p1 = __builtin_amdgcn_exp2f(s[2 * i + 1]);
                lsum += p0 + p1;
                dw[i] = pack2(p0, p1);
            }
            // C-layout -> B-layout (in-register) + PV MFMA
#pragma unroll
            for (int tp = 0; tp < 2; tp++) {
                u32x4 fb;
#if __has_builtin(__builtin_amdgcn_permlane32_swap)
                {
                    auto s02 = __builtin_amdgcn_permlane32_swap(dw[4 * tp + 0], dw[4 * tp + 2], false, false);
                    auto s13 = __builtin_amdgcn_permlane32_swap(dw[4 * tp + 1], dw[4 * tp + 3], false, false);
                    fb[0] = s02[0];
                    fb[1] = s13[0];
                    fb[2] = s02[1];
                    fb[3] = s13[1];
                }
#else
                {
                    const uint32_t a0 = hbit ? dw[4 * tp + 2] : dw[4 * tp + 0];
                    const uint32_t a1 = hbit ? dw[4 * tp + 3] : dw[4 * tp + 1];
                    const uint32_t b0 = hbit ? dw[4 * tp + 0] : dw[4 * tp + 2];
                    const uint32_t b1 = hbit ? dw[4 * tp + 1] : dw[4 * tp + 3];
                    const uint32_t x0 = (uint32_t)__shfl_xor((int)b0, 32);
                    const uint32_t x1 = (uint32_t)__shfl_xor((int)b1, 32);
                    fb[0] = hbit ? x0 : a0;
                    fb[1] = hbit ? x1 : a1;
                    fb[2] = hbit ? a0 : x0;
                    fb[3] = hbit ? a1 : x1;
                }
#endif
                const short8 pfr = __builtin_bit_cast(short8, fb);
                const int kc2 = mc * 2 + tp;
#pragma unroll
                for (int dm = 0; dm < 2; dm++) {
                    const int vrow = dm * 32 + l31;
                    short8 vf = *(const short8*)(stV + vrow * 64 + ((2 * kc2 + hbit) ^ (vrow & 7)) * 8);
                    o[dm] = __builtin_amdgcn_mfma_f32_32x32x16_bf16(vf, pfr, o[dm], 0, 0, 0);
                }
            }
        }
    }

    // ---- combine c-halves (additive), then normalize & store ----
    __syncthreads();
    float4* scr4 = (float4*)&Ks[0][0];   // 8 chunks x 128 lanes x float4 = 16 KB
    float* scrl = (float*)&Vs[0][0];     // 128 floats
    if (wc == 1) {
#pragma unroll
        for (int i = 0; i < 8; i++) {
            float4 c4;
            c4.x = o[i >> 2][(i & 3) * 4 + 0];
            c4.y = o[i >> 2][(i & 3) * 4 + 1];
            c4.z = o[i >> 2][(i & 3) * 4 + 2];
            c4.w = o[i >> 2][(i & 3) * 4 + 3];
            scr4[i * 128 + wq * 64 + lane] = c4;
        }
        scrl[wq * 64 + lane] = lsum;
    }
    __syncthreads();
    if (wc == 0) {
        lsum += scrl[wq * 64 + lane];
#pragma unroll
        for (int i = 0; i < 8; i++) {
            float4 p = scr4[i * 128 + wq * 64 + lane];
            o[i >> 2][(i & 3) * 4 + 0] += p.x;
            o[i >> 2][(i & 3) * 4 + 1] += p.y;
            o[i >> 2][(i & 3) * 4 + 2] += p.z;
            o[i >> 2][(i & 3) * 4 + 3] += p.w;
        }
        lsum += __shfl_xor(lsum, 32);
        const float inv = 1.0f / lsum;
        const int q = q0 + wq * 32 + l31;
        __hip_bfloat16* orow = O + (size_t)(b * QLEN + q) * EMBED + h * HD;
#pragma unroll
        for (int dm = 0; dm < 2; dm++) {
#pragma unroll
            for (int g = 0; g < 4; g++) {
                __hip_bfloat16 ob[4];
#pragma unroll
                for (int r = 0; r < 4; r++) ob[r] = __float2bfloat16(o[dm][g * 4 + r] * inv);
                *(ushort4*)(orow + dm * 32 + hbit * 4 + g * 8) = *(const ushort4*)ob;
            }
        }
    }
}

extern "C" void kernel_launch(void* const* d_in, const int* in_sizes, int n_in,
                              void* d_out, int out_size, void* d_ws, size_t ws_size,
                              hipStream_t stream) {
    const float* query = (const float*)d_in[0];
    const float* context = (const float*)d_in[1];
    const float* Wq = (const float*)d_in[2];
    const float* bq = (const float*)d_in[3];
    const float* Wk = (const float*)d_in[4];
    const float* bk = (const float*)d_in[5];
    const float* Wv = (const float*)d_in[6];
    const float* bv = (const float*)d_in[7];
    const float* Wo = (const float*)d_in[8];
    const float* bo = (const float*)d_in[9];
    float* out = (float*)d_out;

    const int NTOK = BATCH * QLEN;   // 4096
    const int NACT = NTOK * EMBED;   // 4,194,304
    const int NW = EMBED * EMBED;    // 1,048,576

    __hip_bfloat16* qbf = (__hip_bfloat16*)d_ws;
    __hip_bfloat16* cbf = qbf + NACT;
    __hip_bfloat16* Wqt = cbf + NACT;
    __hip_bfloat16* Wkt = Wqt + NW;   // Wkt,Wvt contiguous = fused 2048x1024 B^T
    __hip_bfloat16* Wvt = Wkt + NW;
    __hip_bfloat16* Wot = Wvt + NW;
    __hip_bfloat16* Qp = Wot + NW;
    __hip_bfloat16* Kp = Qp + NACT;
    __hip_bfloat16* Vtr = Kp + NACT;   // V^T ((b*16+h)*64+d) x 2048, written by proj128
    __hip_bfloat16* att = Vtr + NACT;  // attended output

    prep<<<dim3(1024, 6), 256, 0, stream>>>(query, context, qbf, cbf,
                                            Wq, Wk, Wv, Wo, Wqt, Wkt, Wvt, Wot);

    // Q + K + V projections, one dispatch; V written transposed, Q pre-scaled
    proj128<<<768, 256, 0, stream>>>(qbf, cbf, Wqt, Wkt, bq, bk, bv, Qp, Kp, Vtr);

    flash_attn<<<1024, 256, 0, stream>>>(Qp, Kp, Vtr, att);

    oproj<<<512, 256, 0, stream>>>(att, Wot, bo, out);
}